// Round 1
// baseline (630.719 us; speedup 1.0000x reference)
//
#include <hip/hip_runtime.h>

#define DIM 128
#define NB 16   // nodes per block for GEMM-ish kernels

// ---------------- KV projection: K = x@Wk^T+bk, V = x@Wv^T+bv ----------------
__global__ __launch_bounds__(256) void kv_proj(const float* __restrict__ x,
    const float* __restrict__ Wk, const float* __restrict__ bk,
    const float* __restrict__ Wv, const float* __restrict__ bv,
    float* __restrict__ K, float* __restrict__ V, int N) {
  __shared__ float xs[NB * DIM];
  int base = blockIdx.x * NB;
  int tid = threadIdx.x;
  for (int i = tid; i < NB * DIM; i += 256) {
    int nn = i >> 7;
    xs[i] = (base + nn < N) ? x[base * DIM + i] : 0.f;
  }
  __syncthreads();
  int f = tid & 127;
  int mat = tid >> 7;
  const float* W = mat ? Wv : Wk;
  const float* bias = mat ? bv : bk;
  float* O = mat ? V : K;
  float acc[NB];
#pragma unroll
  for (int nn = 0; nn < NB; nn++) acc[nn] = 0.f;
  for (int j = 0; j < DIM; j++) {
    float w = W[f * DIM + j];
#pragma unroll
    for (int nn = 0; nn < NB; nn++) acc[nn] += w * xs[nn * DIM + j];
  }
  float b = bias[f];
  for (int nn = 0; nn < NB; nn++) {
    int n = base + nn;
    if (n < N) O[n * DIM + f] = acc[nn] + b;
  }
}

// ---------------- CSR build ----------------
__global__ __launch_bounds__(256) void hist_kernel(const int* __restrict__ ei,
                                                   int* __restrict__ cnt, int E) {
  int e = blockIdx.x * 256 + threadIdx.x;
  if (e < E) atomicAdd(&cnt[ei[E + e]], 1);  // dst = ei[E..2E)
}

__global__ __launch_bounds__(256) void scanA(const int* __restrict__ cnt,
    int* __restrict__ rs, int* __restrict__ bsum, int N) {
  __shared__ int s[256];
  int t = threadIdx.x;
  int i = blockIdx.x * 256 + t;
  int v = (i < N) ? cnt[i] : 0;
  s[t] = v;
  __syncthreads();
  for (int off = 1; off < 256; off <<= 1) {
    int add = (t >= off) ? s[t - off] : 0;
    __syncthreads();
    s[t] += add;
    __syncthreads();
  }
  if (i < N) rs[i] = s[t] - v;  // exclusive
  if (t == 255) bsum[blockIdx.x] = s[t];
}

__global__ __launch_bounds__(256) void scanB(int* __restrict__ bsum, int nb) {
  __shared__ int s[256];
  int t = threadIdx.x;
  int v = (t < nb) ? bsum[t] : 0;
  s[t] = v;
  __syncthreads();
  for (int off = 1; off < 256; off <<= 1) {
    int add = (t >= off) ? s[t - off] : 0;
    __syncthreads();
    s[t] += add;
    __syncthreads();
  }
  if (t < nb) bsum[t] = s[t] - v;  // exclusive
}

__global__ __launch_bounds__(256) void scanC(int* __restrict__ rs,
    const int* __restrict__ bsum, int* __restrict__ cursor, int N, int E) {
  int i = blockIdx.x * 256 + threadIdx.x;
  if (i < N) {
    int v = rs[i] + bsum[blockIdx.x];
    rs[i] = v;
    cursor[i] = v;
  }
  if (i == 0) rs[N] = E;
}

__global__ __launch_bounds__(256) void scatter_kernel(const int* __restrict__ ei,
    int* __restrict__ cursor, int* __restrict__ esrc, int E) {
  int e = blockIdx.x * 256 + threadIdx.x;
  if (e < E) {
    int d = ei[E + e];
    int pos = atomicAdd(&cursor[d], 1);
    esrc[pos] = ei[e];  // store src node id
  }
}

// ---------------- fused attention aggregate: one wave per dst node ----------
// out[n,h,:] = sum_e V[src_e,h,:]*exp(s_e,h) / sum_e exp(s_e,h)
// (softmax max-subtraction cancels; scores are O(3) so exp is safe)
__global__ __launch_bounds__(256) void attn_agg(const float* __restrict__ K,
    const float* __restrict__ V, const float* __restrict__ x,
    const int* __restrict__ rs, const int* __restrict__ esrc,
    float* __restrict__ attn, int N) {
  int wave = threadIdx.x >> 6, lane = threadIdx.x & 63;
  int n = blockIdx.x * 4 + wave;
  if (n >= N) return;
  float2 xv = *(const float2*)&x[n * DIM + 2 * lane];  // lane owns feats 2l,2l+1 (head l>>3)
  int beg = rs[n], end = rs[n + 1];
  float accx = 0.f, accy = 0.f, dloc = 0.f;
  for (int e = beg; e < end; e++) {
    int src = esrc[e];
    float2 kv = *(const float2*)&K[src * DIM + 2 * lane];
    float p = kv.x * xv.x + kv.y * xv.y;
    p += __shfl_xor(p, 1);
    p += __shfl_xor(p, 2);
    p += __shfl_xor(p, 4);  // lanes 8h..8h+7 now hold full head-h dot
    float ev = expf(p * 0.25f);
    dloc += ev;
    float2 vv = *(const float2*)&V[src * DIM + 2 * lane];
    accx += vv.x * ev;
    accy += vv.y * ev;
  }
  float inv = 1.0f / (dloc + 1e-16f);
  *(float2*)&attn[n * DIM + 2 * lane] = make_float2(accx * inv, accy * inv);
}

// ---------------- O-projection + residual + BN1 stats ----------------
__global__ __launch_bounds__(256) void o_proj_bn(const float* __restrict__ attn,
    const float* __restrict__ x, const float* __restrict__ Wo,
    const float* __restrict__ bo, float* __restrict__ t,
    float* __restrict__ stats, int N) {
  __shared__ float as_[NB * DIM];
  __shared__ float red[512];
  int base = blockIdx.x * NB;
  int tid = threadIdx.x;
  for (int i = tid; i < NB * DIM; i += 256) {
    int nn = i >> 7;
    as_[i] = (base + nn < N) ? attn[base * DIM + i] : 0.f;
  }
  __syncthreads();
  int f = tid & 127, half = tid >> 7;
  float acc[8];
#pragma unroll
  for (int nn = 0; nn < 8; nn++) acc[nn] = 0.f;
  for (int j = 0; j < DIM; j++) {
    float w = Wo[f * DIM + j];
#pragma unroll
    for (int nn = 0; nn < 8; nn++) acc[nn] += w * as_[(half * 8 + nn) * DIM + j];
  }
  float b = bo[f];
  float s = 0.f, ss = 0.f;
  for (int nn = 0; nn < 8; nn++) {
    int n = base + half * 8 + nn;
    if (n < N) {
      float tv = acc[nn] + b + x[n * DIM + f];
      t[n * DIM + f] = tv;
      s += tv;
      ss += tv * tv;
    }
  }
  red[tid] = s;
  red[256 + tid] = ss;
  __syncthreads();
  if (tid < 128) {
    atomicAdd(&stats[tid], red[tid] + red[tid + 128]);
    atomicAdd(&stats[128 + tid], red[256 + tid] + red[256 + tid + 128]);
  }
}

// ---------------- BN finalize: y = t*a + c ----------------
__global__ void bn_fin(const float* __restrict__ stats, const float* __restrict__ g,
                       const float* __restrict__ b, float* __restrict__ coef,
                       float invN) {
  int f = threadIdx.x;  // 128 threads
  float mu = stats[f] * invN;
  float var = stats[128 + f] * invN - mu * mu;
  float a = rsqrtf(var + 1e-5f) * g[f];
  coef[f] = a;
  coef[128 + f] = b[f] - mu * a;
}

// ---------------- FFN (+BN1 apply on input, BN2 stats on output) -------------
__global__ __launch_bounds__(256) void ffn_bn(const float* __restrict__ t,
    const float* __restrict__ coef1, const float* __restrict__ W1,
    const float* __restrict__ b1, const float* __restrict__ W2,
    const float* __restrict__ b2, float* __restrict__ z,
    float* __restrict__ stats2, int N) {
  __shared__ float hs[NB * DIM];
  __shared__ float us[NB * 256];
  __shared__ float red[512];
  int base = blockIdx.x * NB;
  int tid = threadIdx.x;
  for (int i = tid; i < NB * DIM; i += 256) {
    int nn = i >> 7, f = i & 127;
    hs[i] = (base + nn < N) ? t[base * DIM + i] * coef1[f] + coef1[128 + f] : 0.f;
  }
  __syncthreads();
  {  // stage A: u = relu(h@W1^T + b1), 256 feats
    int f = tid;
    float acc[NB];
#pragma unroll
    for (int nn = 0; nn < NB; nn++) acc[nn] = 0.f;
    for (int j = 0; j < DIM; j++) {
      float w = W1[f * DIM + j];
#pragma unroll
      for (int nn = 0; nn < NB; nn++) acc[nn] += w * hs[nn * DIM + j];
    }
    float b = b1[f];
    for (int nn = 0; nn < NB; nn++) us[nn * 256 + f] = fmaxf(acc[nn] + b, 0.f);
  }
  __syncthreads();
  // stage B: z = h + u@W2^T + b2
  int f = tid & 127, half = tid >> 7;
  float acc2[8];
#pragma unroll
  for (int nn = 0; nn < 8; nn++) acc2[nn] = 0.f;
  for (int j = 0; j < 256; j++) {
    float w = W2[f * 256 + j];
#pragma unroll
    for (int nn = 0; nn < 8; nn++) acc2[nn] += w * us[(half * 8 + nn) * 256 + j];
  }
  float b = b2[f];
  float s = 0.f, ss = 0.f;
  for (int nn = 0; nn < 8; nn++) {
    int n = base + half * 8 + nn;
    if (n < N) {
      float zv = hs[(half * 8 + nn) * DIM + f] + acc2[nn] + b;
      z[n * DIM + f] = zv;
      s += zv;
      ss += zv * zv;
    }
  }
  red[tid] = s;
  red[256 + tid] = ss;
  __syncthreads();
  if (tid < 128) {
    atomicAdd(&stats2[tid], red[tid] + red[tid + 128]);
    atomicAdd(&stats2[128 + tid], red[256 + tid] + red[256 + tid + 128]);
  }
}

// ---------------- final BN2 apply ----------------
__global__ __launch_bounds__(256) void final_apply(const float* __restrict__ z,
    const float* __restrict__ coef2, float* __restrict__ out, int total4) {
  int i = blockIdx.x * 256 + threadIdx.x;
  if (i >= total4) return;
  int f = (i * 4) & 127;
  float4 zv = ((const float4*)z)[i];
  float4 o;
  o.x = zv.x * coef2[f] + coef2[128 + f];
  o.y = zv.y * coef2[f + 1] + coef2[128 + f + 1];
  o.z = zv.z * coef2[f + 2] + coef2[128 + f + 2];
  o.w = zv.w * coef2[f + 3] + coef2[128 + f + 3];
  ((float4*)out)[i] = o;
}

extern "C" void kernel_launch(void* const* d_in, const int* in_sizes, int n_in,
                              void* d_out, int out_size, void* d_ws, size_t ws_size,
                              hipStream_t stream) {
  const float* x = (const float*)d_in[0];
  const int* ei = (const int*)d_in[1];
  const float* Wk = (const float*)d_in[2];
  const float* bk = (const float*)d_in[3];
  const float* Wv = (const float*)d_in[4];
  const float* bv = (const float*)d_in[5];
  const float* Wo = (const float*)d_in[6];
  const float* bo = (const float*)d_in[7];
  const float* bn1_g = (const float*)d_in[8];
  const float* bn1_b = (const float*)d_in[9];
  const float* W1 = (const float*)d_in[10];
  const float* b1 = (const float*)d_in[11];
  const float* W2 = (const float*)d_in[12];
  const float* b2 = (const float*)d_in[13];
  const float* bn2_g = (const float*)d_in[14];
  const float* bn2_b = (const float*)d_in[15];
  float* out = (float*)d_out;

  int N = in_sizes[0] / DIM;   // 40000
  int E = in_sizes[1] / 2;     // 640000

  // workspace layout (t reuses K, z reuses V — dead by then)
  float* Kbuf = (float*)d_ws;
  float* Vbuf = Kbuf + (size_t)N * DIM;
  float* attn = Vbuf + (size_t)N * DIM;
  float* tbuf = Kbuf;
  float* zbuf = Vbuf;
  float* stats = attn + (size_t)N * DIM;  // 512 floats: stats1 | stats2
  float* coef = stats + 512;              // 512 floats: a1,c1 | a2,c2
  int* cnt = (int*)(coef + 512);
  int* rs = cnt + N;          // N+1
  int* cursor = rs + N + 1;   // N
  int* esrc = cursor + N;     // E
  int* bsum = esrc + E;       // up to 256

  int nblk = (N + 255) / 256;  // 157 (must be <= 256 for scanB)

  hipMemsetAsync(cnt, 0, (size_t)N * sizeof(int), stream);
  hipMemsetAsync(stats, 0, 512 * sizeof(float), stream);

  kv_proj<<<(N + NB - 1) / NB, 256, 0, stream>>>(x, Wk, bk, Wv, bv, Kbuf, Vbuf, N);
  hist_kernel<<<(E + 255) / 256, 256, 0, stream>>>(ei, cnt, E);
  scanA<<<nblk, 256, 0, stream>>>(cnt, rs, bsum, N);
  scanB<<<1, 256, 0, stream>>>(bsum, nblk);
  scanC<<<nblk, 256, 0, stream>>>(rs, bsum, cursor, N, E);
  scatter_kernel<<<(E + 255) / 256, 256, 0, stream>>>(ei, cursor, esrc, E);
  attn_agg<<<(N + 3) / 4, 256, 0, stream>>>(Kbuf, Vbuf, x, rs, esrc, attn, N);
  o_proj_bn<<<(N + NB - 1) / NB, 256, 0, stream>>>(attn, x, Wo, bo, tbuf, stats, N);
  bn_fin<<<1, 128, 0, stream>>>(stats, bn1_g, bn1_b, coef, 1.0f / N);
  ffn_bn<<<(N + NB - 1) / NB, 256, 0, stream>>>(tbuf, coef, W1, b1, W2, b2, zbuf,
                                                stats + 256, N);
  bn_fin<<<1, 128, 0, stream>>>(stats + 256, bn2_g, bn2_b, coef + 256, 1.0f / N);
  final_apply<<<((N * DIM / 4) + 255) / 256, 256, 0, stream>>>(zbuf, coef + 256, out,
                                                               N * DIM / 4);
}